// Round 3
// baseline (486.327 us; speedup 1.0000x reference)
//
#include <hip/hip_runtime.h>
#include <hip/hip_bf16.h>

// Problem constants (match setup_inputs): B=2, N=512, D=128, H=256.
#define BB 2
#define NN 512
#define DD 128
#define HH 256

typedef __attribute__((ext_vector_type(4))) float  f32x4;
typedef __attribute__((ext_vector_type(8))) short  s16x8;  // 8 bf16 (MFMA A/B frag)
typedef __attribute__((ext_vector_type(4))) int    i32x4;

__device__ __forceinline__ float bf16u(short u) {
  return __int_as_float(((int)(unsigned short)u) << 16);
}
// VALU-pipe 16-lane reduce step (DPP).
template <int CTRL>
__device__ __forceinline__ float dpp_add(float x) {
  int s = __builtin_amdgcn_update_dpp(0, __float_as_int(x), CTRL, 0xF, 0xF, true);
  return x + __int_as_float(s);
}

// ---------------------------------------------------------------------------
// Stage 1: hA[b,n,h] = bf16(b1[h] + sum_d PhiA*W1[:D]);  hB = bf16(PhiB*W1[D:])
// ---------------------------------------------------------------------------
#define S1_ROWS 8
__global__ __launch_bounds__(256) void stage1(
    const float* __restrict__ PhiA, const float* __restrict__ PhiB,
    const float* __restrict__ W1,  const float* __restrict__ b1,
    __hip_bfloat16* __restrict__ hA, __hip_bfloat16* __restrict__ hB) {
  __shared__ float phis[S1_ROWS * DD];  // 4 KB
  const int side = blockIdx.x & 1;
  const int row0 = (blockIdx.x >> 1) * S1_ROWS;
  const float* Phi = side ? PhiB : PhiA;
  const float* W   = W1 + side * DD * HH;
  ((f32x4*)phis)[threadIdx.x] =
      ((const f32x4*)(Phi + (size_t)row0 * DD))[threadIdx.x];
  __syncthreads();
  const int h = threadIdx.x;
  float acc[S1_ROWS];
#pragma unroll
  for (int i = 0; i < S1_ROWS; i++) acc[i] = 0.f;
  for (int d0 = 0; d0 < DD; d0 += 4) {
    const float w0 = W[(d0 + 0) * HH + h];
    const float w1 = W[(d0 + 1) * HH + h];
    const float w2 = W[(d0 + 2) * HH + h];
    const float w3 = W[(d0 + 3) * HH + h];
#pragma unroll
    for (int i = 0; i < S1_ROWS; i++) {
      f32x4 ph = *(const f32x4*)&phis[i * DD + d0];
      acc[i] = fmaf(ph.x, w0, acc[i]);
      acc[i] = fmaf(ph.y, w1, acc[i]);
      acc[i] = fmaf(ph.z, w2, acc[i]);
      acc[i] = fmaf(ph.w, w3, acc[i]);
    }
  }
  const float bias = side ? 0.f : b1[h];
  __hip_bfloat16* o = (side ? hB : hA) + (size_t)row0 * HH + h;
#pragma unroll
  for (int i = 0; i < S1_ROWS; i++) o[i * HH] = __float2bfloat16(acc[i] + bias);
}

// ---------------------------------------------------------------------------
// W2 [k][col] f32  ->  W2t [col][k] bf16
// ---------------------------------------------------------------------------
__global__ __launch_bounds__(256) void prep_w2(
    const float* __restrict__ W2, __hip_bfloat16* __restrict__ W2t) {
  const int col = blockIdx.x;
  const int k   = threadIdx.x;
  W2t[col * HH + k] = __float2bfloat16(W2[k * HH + col]);
}

// ---------------------------------------------------------------------------
// Main fused kernel. 4 waves/block; wave w owns cols [w*64, w*64+64).
// W2 fragments re-read from L2 each K-step (frees 128 VGPRs -> 4 waves/SIMD).
// Per iter: ONE barrier; h1 double-buffered; DPP epilogue; partials to red[]
// LDS; previous iter's outputs plain-stored after the barrier (no atomics).
// ---------------------------------------------------------------------------
#define GRID_MAIN 1024
#define KITERS 16

__global__ __launch_bounds__(256, 4) void pairmlp(
    const __hip_bfloat16* __restrict__ hA, const __hip_bfloat16* __restrict__ hB,
    const __hip_bfloat16* __restrict__ W2t, const float* __restrict__ b2,
    const float* __restrict__ W3, const float* __restrict__ b3,
    float* __restrict__ out) {
  __shared__ __align__(16) short h1[2][32 * 256];  // 2 x 16 KB, swizzled bf16
  __shared__ float red[2][4][32];                  // partials, dbuf by iter parity

  const int tid  = threadIdx.x;
  const int lane = tid & 63;
  const int w    = tid >> 6;   // wave 0..3
  const int g    = lane >> 4;  // 0..3
  const int lr   = lane & 15;
  const int bid  = blockIdx.x;
  const int bb    = bid >> 9;              // batch
  const int m0    = ((bid >> 4) & 31) * 16; // fixed per block
  const int nbase = bid & 15;              // 0..15

  float b2v[4], w3v[4];
#pragma unroll
  for (int ct = 0; ct < 4; ct++) {
    const int col = w * 64 + ct * 16 + lr;
    b2v[ct] = b2[col];
    w3v[ct] = W3[col];
  }
  const float b3v = b3[0];
  // W2 fragment base for this lane: frag(ks,ct) at wb + ct*16*HH + ks*32
  const __hip_bfloat16* wb = W2t + (size_t)(w * 64 + lr) * HH + g * 8;

  const int p = tid >> 3;  // 0..31: pair row for construction
  const int c = tid & 7;   // k-chunk of 32

  // ---- loop-invariant hB row chunk in registers (bf16) ----
  s16x8 hbr[4];
  {
    const __hip_bfloat16* hBp =
        hB + ((size_t)(bb * NN + m0 + (p & 15))) * HH + c * 32;
#pragma unroll
    for (int q = 0; q < 4; q++)
      hbr[q] = *reinterpret_cast<const s16x8*>(hBp + q * 8);
  }
  const __hip_bfloat16* hAbase =
      hA + ((size_t)(bb * NN + (p >> 4))) * HH + c * 32;

  auto loadA = [&](int n0, s16x8* av) {
    const __hip_bfloat16* hAp = hAbase + (size_t)n0 * HH;
#pragma unroll
    for (int q = 0; q < 4; q++)
      av[q] = *reinterpret_cast<const s16x8*>(hAp + q * 8);
  };
  auto build = [&](const s16x8* av, int buf) {
#pragma unroll
    for (int q = 0; q < 4; q++) {
      int pk[4];
#pragma unroll
      for (int jj = 0; jj < 4; jj++) {
        float r0 = fmaxf(bf16u(av[q][2 * jj])     + bf16u(hbr[q][2 * jj]),     0.f);
        float r1 = fmaxf(bf16u(av[q][2 * jj + 1]) + bf16u(hbr[q][2 * jj + 1]), 0.f);
        union { __hip_bfloat162 hh; int ii; } u;
        u.hh = __float22bfloat162_rn(make_float2(r0, r1));
        pk[jj] = u.ii;
      }
      i32x4 pv = {pk[0], pk[1], pk[2], pk[3]};
      const int addr = (p * 512 + c * 64 + q * 16) ^ ((p & 7) << 4);
      *reinterpret_cast<i32x4*>(reinterpret_cast<char*>(h1[buf]) + addr) = pv;
    }
  };

  // prologue: construct tile k=0 into buffer 0
  {
    s16x8 av[4];
    loadA(2 * nbase, av);
    build(av, 0);
  }

  for (int k = 0; k < KITERS; k++) {
    const int cur = k & 1;
    const int n0  = 2 * (nbase + 16 * k);
    __syncthreads();  // h1[cur] + red[cur^1] ready; WAR on h1[cur^1] resolved

    // issue next tile's hA loads early
    s16x8 av[4];
    if (k < KITERS - 1) loadA(n0 + 32, av);

    // store previous iter's reduced outputs (ordered by the barrier above)
    if (k > 0 && tid < 32) {
      const int pb = cur ^ 1;
      const float v = red[pb][0][tid] + red[pb][1][tid] + red[pb][2][tid] +
                      red[pb][3][tid] + b3v;
      const int n = (n0 - 32) + (tid >> 4);
      out[((size_t)(bb * NN + n)) * NN + m0 + (tid & 15)] = v;
    }

    // ---- MFMA: 8 K-steps; W2 fragments JIT-loaded from L2 ----
    f32x4 acc[2][4];
#pragma unroll
    for (int rt = 0; rt < 2; rt++)
#pragma unroll
      for (int ct = 0; ct < 4; ct++) acc[rt][ct] = (f32x4){0.f, 0.f, 0.f, 0.f};
#pragma unroll
    for (int ks = 0; ks < 8; ks++) {
      s16x8 bfrag[4];
#pragma unroll
      for (int ct = 0; ct < 4; ct++)
        bfrag[ct] = *reinterpret_cast<const s16x8*>(wb + ct * (16 * HH) + ks * 32);
      s16x8 afrag[2];
#pragma unroll
      for (int rt = 0; rt < 2; rt++) {
        const int row  = rt * 16 + lr;
        const int addr = (row * 512 + ks * 64 + g * 16) ^ ((row & 7) << 4);
        afrag[rt] = *reinterpret_cast<const s16x8*>(
            reinterpret_cast<const char*>(h1[cur]) + addr);
      }
#pragma unroll
      for (int rt = 0; rt < 2; rt++)
#pragma unroll
        for (int ct = 0; ct < 4; ct++)
          acc[rt][ct] = __builtin_amdgcn_mfma_f32_16x16x32_bf16(
              afrag[rt], bfrag[ct], acc[rt][ct], 0, 0, 0);
    }

    // construct next tile into the other buffer
    if (k < KITERS - 1) build(av, cur ^ 1);

    // ---- epilogue: DPP 16-lane reduce, partials into red[cur] ----
    float part[2][4];
#pragma unroll
    for (int rt = 0; rt < 2; rt++)
#pragma unroll
      for (int r = 0; r < 4; r++) {
        float s = 0.f;
#pragma unroll
        for (int ct = 0; ct < 4; ct++)
          s += fmaxf(acc[rt][ct][r] + b2v[ct], 0.f) * w3v[ct];
        s = dpp_add<0xB1>(s);    // + lane^1
        s = dpp_add<0x4E>(s);    // + lane^2
        s = dpp_add<0x141>(s);   // + other quad (row_half_mirror)
        s = dpp_add<0x140>(s);   // + other 8-group (row_mirror)
        part[rt][r] = s;
      }
    if (lr == 0) {
#pragma unroll
      for (int rt = 0; rt < 2; rt++)
#pragma unroll
        for (int r = 0; r < 4; r++)
          red[cur][w][rt * 16 + g * 4 + r] = part[rt][r];
    }
  }

  // tail: store the last iter's outputs
  __syncthreads();
  if (tid < 32) {
    const int pb = (KITERS - 1) & 1;
    const float v = red[pb][0][tid] + red[pb][1][tid] + red[pb][2][tid] +
                    red[pb][3][tid] + b3v;
    const int n = 2 * (nbase + 16 * (KITERS - 1)) + (tid >> 4);
    out[((size_t)(bb * NN + n)) * NN + m0 + (tid & 15)] = v;
  }
}

// ---------------------------------------------------------------------------
extern "C" void kernel_launch(void* const* d_in, const int* in_sizes, int n_in,
                              void* d_out, int out_size, void* d_ws, size_t ws_size,
                              hipStream_t stream) {
  const float* PhiA = (const float*)d_in[0];
  const float* PhiB = (const float*)d_in[1];
  const float* W1   = (const float*)d_in[2];
  const float* b1   = (const float*)d_in[3];
  const float* W2   = (const float*)d_in[4];
  const float* b2   = (const float*)d_in[5];
  const float* W3   = (const float*)d_in[6];
  const float* b3   = (const float*)d_in[7];
  float* out = (float*)d_out;

  char* ws = (char*)d_ws;
  __hip_bfloat16* hA  = (__hip_bfloat16*)ws;                    // 512 KB
  __hip_bfloat16* hB  = (__hip_bfloat16*)(ws + (512u << 10));   // 512 KB
  __hip_bfloat16* W2t = (__hip_bfloat16*)(ws + (1024u << 10));  // 128 KB

  hipLaunchKernelGGL(stage1, dim3(2 * (BB * NN) / S1_ROWS), dim3(256), 0, stream,
                     PhiA, PhiB, W1, b1, hA, hB);
  hipLaunchKernelGGL(prep_w2, dim3(HH), dim3(256), 0, stream, W2, W2t);
  hipLaunchKernelGGL(pairmlp, dim3(GRID_MAIN), dim3(256), 0, stream,
                     hA, hB, W2t, b2, W3, b3, out);
}

// Round 5
// 150.992 us; speedup vs baseline: 3.2209x; 3.2209x over previous
//
#include <hip/hip_runtime.h>
#include <hip/hip_bf16.h>

// Problem constants (match setup_inputs): B=2, N=512, D=128, H=256.
#define BB 2
#define NN 512
#define DD 128
#define HH 256

typedef __attribute__((ext_vector_type(4))) float    f32x4;
typedef __attribute__((ext_vector_type(8))) _Float16 f16x8;  // 4 VGPRs
typedef __attribute__((ext_vector_type(4))) int      i32x4;

union F16x8 {
  f16x8 v;
  i32x4 i;
};

// VALU-pipe 16-lane reduce step (DPP).
template <int CTRL>
__device__ __forceinline__ float dpp_add(float x) {
  int s = __builtin_amdgcn_update_dpp(0, __float_as_int(x), CTRL, 0xF, 0xF, true);
  return x + __int_as_float(s);
}

// ---------------------------------------------------------------------------
// Stage 1 (+W2 prep in extra blocks):
//   hA[b,n,h] = f16(b1[h] + sum_d PhiA*W1[:D]);  hB = f16(PhiB*W1[D:])
//   W2t[col][k] = f16(W2[k][col])
// ---------------------------------------------------------------------------
#define S1_ROWS 8
#define S1_BLOCKS (2 * (BB * NN) / S1_ROWS)  // 512
__global__ __launch_bounds__(256) void stage1(
    const float* __restrict__ PhiA, const float* __restrict__ PhiB,
    const float* __restrict__ W1,  const float* __restrict__ b1,
    const float* __restrict__ W2,
    _Float16* __restrict__ hA, _Float16* __restrict__ hB,
    _Float16* __restrict__ W2t) {
  if (blockIdx.x >= S1_BLOCKS) {  // W2 transpose+cast: 8 blocks
    const int bid2 = blockIdx.x - S1_BLOCKS;       // 0..7
    const int col  = bid2 * 32 + (threadIdx.x >> 3);
    const int k0   = (threadIdx.x & 7) * 32;
#pragma unroll
    for (int j = 0; j < 32; j++)
      W2t[col * HH + k0 + j] = (_Float16)W2[(k0 + j) * HH + col];
    return;
  }
  __shared__ float phis[S1_ROWS * DD];  // 4 KB
  const int side = blockIdx.x & 1;
  const int row0 = (blockIdx.x >> 1) * S1_ROWS;
  const float* Phi = side ? PhiB : PhiA;
  const float* W   = W1 + side * DD * HH;
  ((f32x4*)phis)[threadIdx.x] =
      ((const f32x4*)(Phi + (size_t)row0 * DD))[threadIdx.x];
  __syncthreads();
  const int h = threadIdx.x;
  float acc[S1_ROWS];
#pragma unroll
  for (int i = 0; i < S1_ROWS; i++) acc[i] = 0.f;
  for (int d0 = 0; d0 < DD; d0 += 4) {
    const float w0 = W[(d0 + 0) * HH + h];
    const float w1 = W[(d0 + 1) * HH + h];
    const float w2 = W[(d0 + 2) * HH + h];
    const float w3 = W[(d0 + 3) * HH + h];
#pragma unroll
    for (int i = 0; i < S1_ROWS; i++) {
      f32x4 ph = *(const f32x4*)&phis[i * DD + d0];
      acc[i] = fmaf(ph.x, w0, acc[i]);
      acc[i] = fmaf(ph.y, w1, acc[i]);
      acc[i] = fmaf(ph.z, w2, acc[i]);
      acc[i] = fmaf(ph.w, w3, acc[i]);
    }
  }
  const float bias = side ? 0.f : b1[h];
  _Float16* o = (side ? hB : hA) + (size_t)row0 * HH + h;
#pragma unroll
  for (int i = 0; i < S1_ROWS; i++) o[i * HH] = (_Float16)(acc[i] + bias);
}

// ---------------------------------------------------------------------------
// Main fused kernel. 512 threads = 8 waves; wave w owns cols [w*32, w*32+32)
// (breg = 16 f16x8 = 64 VGPRs -> ~115 regs total -> 4 waves/SIMD, 2 blk/CU).
// Per iter: ONE barrier; h1 (f16, XOR-swizzled) double-buffered; packed-f16
// build (v_pk_add_f16 / v_pk_max_f16, no unpack); DPP epilogue; red[] dbuf;
// plain coalesced stores one iter deferred.
// ---------------------------------------------------------------------------
#define GRID_MAIN 512
#define KITERS 32

__global__ __launch_bounds__(512, 4) void pairmlp(
    const _Float16* __restrict__ hA, const _Float16* __restrict__ hB,
    const _Float16* __restrict__ W2t, const float* __restrict__ b2,
    const float* __restrict__ W3, const float* __restrict__ b3,
    float* __restrict__ out) {
  __shared__ __align__(16) short h1[2][32 * 256];  // 2 x 16 KB, swizzled f16
  __shared__ float red[2][8][32];                  // partials, dbuf by parity

  const int tid  = threadIdx.x;
  const int lane = tid & 63;
  const int w    = tid >> 6;   // wave 0..7
  const int g    = lane >> 4;  // 0..3
  const int lr   = lane & 15;
  const int bid  = blockIdx.x;
  const int bb    = bid >> 8;               // batch
  const int m0    = ((bid >> 3) & 31) * 16; // fixed per block
  const int nbase = bid & 7;                // 0..7

  // ---- persistent W2 fragments: 8 ks x 2 ct = 64 VGPRs ----
  f16x8 breg[8][2];
#pragma unroll
  for (int ks = 0; ks < 8; ks++)
#pragma unroll
    for (int ct = 0; ct < 2; ct++) {
      const int col = w * 32 + ct * 16 + lr;
      breg[ks][ct] = *reinterpret_cast<const f16x8*>(&W2t[col * HH + ks * 32 + g * 8]);
    }
  float b2v[2], w3v[2];
#pragma unroll
  for (int ct = 0; ct < 2; ct++) {
    const int col = w * 32 + ct * 16 + lr;
    b2v[ct] = b2[col];
    w3v[ct] = W3[col];
  }
  const float b3v = b3[0];

  const int p  = tid >> 4;  // 0..31: pair row for construction
  const int c4 = tid & 15;  // k-chunk of 16

  // ---- loop-invariant hB chunk (f16, 8 VGPRs) ----
  F16x8 hbr[2];
  {
    const _Float16* hBp = hB + ((size_t)(bb * NN + m0 + (p & 15))) * HH + c4 * 16;
#pragma unroll
    for (int q = 0; q < 2; q++)
      hbr[q].v = *reinterpret_cast<const f16x8*>(hBp + q * 8);
  }
  const _Float16* hAbase = hA + ((size_t)(bb * NN + (p >> 4))) * HH + c4 * 16;

  auto loadA = [&](int n0, F16x8* av) {
    const _Float16* hAp = hAbase + (size_t)n0 * HH;
#pragma unroll
    for (int q = 0; q < 2; q++)
      av[q].v = *reinterpret_cast<const f16x8*>(hAp + q * 8);
  };
  auto build = [&](const F16x8* av, int buf) {
    const f16x8 zero8 = {};
#pragma unroll
    for (int q = 0; q < 2; q++) {
      F16x8 r;
      r.v = __builtin_elementwise_max(av[q].v + hbr[q].v, zero8);
      const int addr = (p * 512 + c4 * 32 + q * 16) ^ ((p & 7) << 4);
      *reinterpret_cast<i32x4*>(reinterpret_cast<char*>(h1[buf]) + addr) = r.i;
    }
  };

  // prologue: construct tile k=0 into buffer 0
  {
    F16x8 av[2];
    loadA(2 * nbase, av);
    build(av, 0);
  }

  for (int k = 0; k < KITERS; k++) {
    const int cur = k & 1;
    const int n0  = 2 * (nbase + 8 * k);
    __syncthreads();  // h1[cur] + red[cur^1] ready; WAR on h1[cur^1] resolved

    // issue next tile's hA loads early (hidden under MFMA)
    F16x8 av[2];
    if (k < KITERS - 1) loadA(n0 + 16, av);

    // store previous iter's reduced outputs (ordered by the barrier above)
    if (k > 0 && tid < 32) {
      const int pb = cur ^ 1;
      float v = b3v;
#pragma unroll
      for (int ww = 0; ww < 8; ww++) v += red[pb][ww][tid];
      const int n = (n0 - 16) + (tid >> 4);
      out[((size_t)(bb * NN + n)) * NN + m0 + (tid & 15)] = v;
    }

    // ---- MFMA: 8 K-steps x (2 row-tiles x 2 col-tiles) ----
    f32x4 acc[2][2];
#pragma unroll
    for (int rt = 0; rt < 2; rt++)
#pragma unroll
      for (int ct = 0; ct < 2; ct++) acc[rt][ct] = (f32x4){0.f, 0.f, 0.f, 0.f};
#pragma unroll
    for (int ks = 0; ks < 8; ks++) {
      f16x8 afrag[2];
#pragma unroll
      for (int rt = 0; rt < 2; rt++) {
        const int row  = rt * 16 + lr;
        const int addr = (row * 512 + ks * 64 + g * 16) ^ ((row & 7) << 4);
        afrag[rt] = *reinterpret_cast<const f16x8*>(
            reinterpret_cast<const char*>(h1[cur]) + addr);
      }
#pragma unroll
      for (int rt = 0; rt < 2; rt++)
#pragma unroll
        for (int ct = 0; ct < 2; ct++)
          acc[rt][ct] = __builtin_amdgcn_mfma_f32_16x16x32_f16(
              afrag[rt], breg[ks][ct], acc[rt][ct], 0, 0, 0);
    }

    // construct next tile into the other buffer
    if (k < KITERS - 1) build(av, cur ^ 1);

    // ---- epilogue: relu(.+b2)*w3, DPP 16-lane reduce, partials to red ----
    float part[2][4];
#pragma unroll
    for (int rt = 0; rt < 2; rt++)
#pragma unroll
      for (int r = 0; r < 4; r++) {
        float s = fmaxf(acc[rt][0][r] + b2v[0], 0.f) * w3v[0];
        s = fmaf(fmaxf(acc[rt][1][r] + b2v[1], 0.f), w3v[1], s);
        s = dpp_add<0xB1>(s);    // + lane^1
        s = dpp_add<0x4E>(s);    // + lane^2
        s = dpp_add<0x141>(s);   // + other quad (row_half_mirror)
        s = dpp_add<0x140>(s);   // + other 8-group (row_mirror)
        part[rt][r] = s;
      }
    if (lr == 0) {
#pragma unroll
      for (int rt = 0; rt < 2; rt++)
#pragma unroll
        for (int r = 0; r < 4; r++)
          red[cur][w][rt * 16 + g * 4 + r] = part[rt][r];
    }
  }

  // tail: store the last iter's outputs
  __syncthreads();
  if (tid < 32) {
    const int pb = (KITERS - 1) & 1;
    float v = b3v;
#pragma unroll
    for (int ww = 0; ww < 8; ww++) v += red[pb][ww][tid];
    const int n = 2 * (nbase + 8 * (KITERS - 1)) + (tid >> 4);
    out[((size_t)(bb * NN + n)) * NN + m0 + (tid & 15)] = v;
  }
}

// ---------------------------------------------------------------------------
extern "C" void kernel_launch(void* const* d_in, const int* in_sizes, int n_in,
                              void* d_out, int out_size, void* d_ws, size_t ws_size,
                              hipStream_t stream) {
  const float* PhiA = (const float*)d_in[0];
  const float* PhiB = (const float*)d_in[1];
  const float* W1   = (const float*)d_in[2];
  const float* b1   = (const float*)d_in[3];
  const float* W2   = (const float*)d_in[4];
  const float* b2   = (const float*)d_in[5];
  const float* W3   = (const float*)d_in[6];
  const float* b3   = (const float*)d_in[7];
  float* out = (float*)d_out;

  char* ws = (char*)d_ws;
  _Float16* hA  = (_Float16*)ws;                    // 512 KB
  _Float16* hB  = (_Float16*)(ws + (512u << 10));   // 512 KB
  _Float16* W2t = (_Float16*)(ws + (1024u << 10));  // 128 KB

  hipLaunchKernelGGL(stage1, dim3(S1_BLOCKS + 8), dim3(256), 0, stream,
                     PhiA, PhiB, W1, b1, W2, hA, hB, W2t);
  hipLaunchKernelGGL(pairmlp, dim3(GRID_MAIN), dim3(512), 0, stream,
                     hA, hB, W2t, b2, W3, b3, out);
}